// Round 2
// baseline (313.942 us; speedup 1.0000x reference)
//
#include <hip/hip_runtime.h>

// Dims: x,x1,x2:(8,512,32,32) fp32; w1:(256,512,1,1); b1:(256); w2:(512,256,3,3);
// b2:(512); gamma,bn_bias:(512); beta:(1). Out:(8,512,32,32) fp32.
// G = 16 images (8 from x1, 8 from x2), N = 1024 spatial.
//
// GEMM operands (except conv2 weights) are stored as pre-swizzled "LDS images":
// per (z, panel(128 rows), kc(64 k)) a 32 KB block of 128 rows x 256 B; row r
// holds 16 chunks of 16 B at slot ((c&7)^(r&7))|(c&8); hi chunks c=0..7
// (k=c*8+e), lo c=8..15 (always hi+128 B). Staging is then pure global_load_lds.
//
// conv2 weights (w2s) use a REGISTER-FRAGMENT layout: per (panel, chunk, dy, dx)
// phase P = (panel*8+chunk)*9+dy*3+dx, a 16 KB block:
//   byte = P*16384 + coh*8192 + (j*2+hl)*1024 + lane*16 + e*2
// with co = panel*128+coh*64+j*16+(lane&15), ci = chunk*32+(lane>>4)*8+e.
// The conv kernel loads A-fragments straight to VGPRs with an explicit
// one-phase register prefetch pipeline (round 8): phase p issues loads for
// p+1 into Wn while MFMAs consume Wc (no vmcnt stall on the critical path).
//
// ws layout (byte offsets), total 55,091,200 B (unchanged):
//  [0        , 33554432) RF : x12t image -> F image (conv2 out) -> xt image
//                         [0,16777216) + att image [16777216, 25165824)
//  [33554432 , 50331648) RY : Y1 conv-input image (16,777,216 B exactly)
//                         -> S0 fp32 [33554432,+8388608) + S1 [+8388608)
//  [50331648 , 55050240) w2s weight fragments
//  [55050240 , 55058432) stats ; [55058432, 55091200) rowsum

typedef __attribute__((ext_vector_type(8))) short bfrag;   // 8 bf16 = 4 VGPR
typedef __attribute__((ext_vector_type(4))) float facc;    // 4 fp32 acc

__device__ __forceinline__ unsigned short bf16_rn(float v) {
  unsigned u = __float_as_uint(v);
  return (unsigned short)((u + 0x7fffu + ((u >> 16) & 1u)) >> 16);
}

// async global -> LDS, 16 B per lane; global addr is per-lane (include lane*16),
// LDS base is wave-uniform (HW adds lane*16).
__device__ __forceinline__ void dma16(const void* g, const void* lds) {
  __builtin_amdgcn_global_load_lds(
      (const __attribute__((address_space(1))) unsigned int*)g,
      (__attribute__((address_space(3))) unsigned int*)(unsigned int)(unsigned long long)(const char*)lds,
      16, 0, 0);
}

// Prologue: blocks [0,8192): x1/x2 -> x12t image; blocks [8192,8704): w2s + stats zero.
__global__ __launch_bounds__(256) void prologue(
    const float* __restrict__ x1, const float* __restrict__ x2,
    const float* __restrict__ w2, unsigned char* __restrict__ x12timg,
    unsigned short* __restrict__ w2s, float* __restrict__ statsz) {
  int bid = blockIdx.x;
  int t = threadIdx.x;
  if (bid < 8192) {
    __shared__ float tile[32][33];
    int p0 = (bid & 31) * 32, ci0 = ((bid >> 5) & 15) * 32, z = bid >> 9;
    const float* src = (z < 8) ? x1 + (size_t)z * 524288 : x2 + (size_t)(z - 8) * 524288;
    {
      int ci_l = t >> 5, p_l = t & 31;
#pragma unroll
      for (int j = 0; j < 4; j++)
        tile[ci_l + 8 * j][p_l] = src[(size_t)(ci0 + ci_l + 8 * j) * 1024 + p0 + p_l];
    }
    __syncthreads();
    {
      int p_l = t >> 3, cg = (t & 7) * 4;
      unsigned short hh[4], ll[4];
#pragma unroll
      for (int j = 0; j < 4; j++) {
        float v = tile[cg + j][p_l];
        hh[j] = bf16_rn(v);
        ll[j] = bf16_rn(v - __uint_as_float((unsigned)hh[j] << 16));
      }
      int px = p0 + p_l, row = px & 127, panel = px >> 7;
      int c = ci0 + cg, kc = c >> 6, ck = (c >> 3) & 7;
      int slot = ck ^ (row & 7);
      size_t byte = (((size_t)(z * 8 + panel) * 8 + kc) * 128 + row) * 256 + slot * 16 + (c & 7) * 2;
      *(ushort4*)(x12timg + byte) = make_ushort4(hh[0], hh[1], hh[2], hh[3]);
      *(ushort4*)(x12timg + byte + 128) = make_ushort4(ll[0], ll[1], ll[2], ll[3]);
    }
  } else {
    int co = bid - 8192;  // 0..511
    if (co < 40) statsz[co * 256 + t] = 0.f;
    // register-fragment weight layout:
    // co -> (panel, coh, j, lm); ci=t -> (chunk, q, e); lane = q*16+lm
    int panel = co >> 7, coh = (co >> 6) & 1, jf = (co >> 4) & 3, lmv = co & 15;
    int chunk = t >> 5, qv = (t >> 3) & 3, e = t & 7;
    int lanev = qv * 16 + lmv;
    const float* src = w2 + ((size_t)co * 256 + t) * 9;
#pragma unroll
    for (int tap = 0; tap < 9; tap++) {
      float v = src[tap];
      unsigned short h = bf16_rn(v);
      unsigned short l = bf16_rn(v - __uint_as_float((unsigned)h << 16));
      int P = (panel * 8 + chunk) * 9 + tap;  // tap = dy*3+dx
      size_t us = (((size_t)(P * 2 + coh) * 8 + jf * 2) * 512) + lanev * 8 + e;
      w2s[us] = h;        // hl=0
      w2s[us + 512] = l;  // hl=1
    }
  }
}

// x fp32 [z][512 c][1024 px] -> xt image (B operand rows=px, k=c).
__global__ __launch_bounds__(256) void transpose_split_x(
    const float* __restrict__ x, unsigned char* __restrict__ img) {
  __shared__ float tile[32][33];
  int z = blockIdx.z;
  const float* src = x + (size_t)z * 524288;
  int ci0 = blockIdx.y * 32, p0 = blockIdx.x * 32;
  int t = threadIdx.x;
  {
    int ci_l = t >> 5, p_l = t & 31;
#pragma unroll
    for (int j = 0; j < 4; j++)
      tile[ci_l + 8 * j][p_l] = src[(size_t)(ci0 + ci_l + 8 * j) * 1024 + p0 + p_l];
  }
  __syncthreads();
  {
    int p_l = t >> 3, cg = (t & 7) * 4;
    unsigned short hh[4], ll[4];
#pragma unroll
    for (int j = 0; j < 4; j++) {
      float v = tile[cg + j][p_l];
      hh[j] = bf16_rn(v);
      ll[j] = bf16_rn(v - __uint_as_float((unsigned)hh[j] << 16));
    }
    int px = p0 + p_l, row = px & 127, panel = px >> 7;
    int c = ci0 + cg, kc = c >> 6, ck = (c >> 3) & 7;
    int slot = ck ^ (row & 7);
    size_t byte = (((size_t)(z * 8 + panel) * 8 + kc) * 128 + row) * 256 + slot * 16 + (c & 7) * 2;
    *(ushort4*)(img + byte) = make_ushort4(hh[0], hh[1], hh[2], hh[3]);
    *(ushort4*)(img + byte + 128) = make_ushort4(ll[0], ll[1], ll[2], ll[3]);
  }
}

// Split-bf16 3-pass NT MFMA GEMM on pre-swizzled images.
// Block tile 128m x 64n, 256 threads, 4 waves 2x2, wave tile 64m x 32n
// (4x2 tiles of 16x16x32). K-step 64. A/B staged via global_load_lds (image
// memcpy); AF32=1: A is fp32 w1, split in-register. KSPLIT: z = kh*8+zb,
// kc = kh*(KTOT/64)+k0/64, EPI1 partial to S+kh*2097152 (affine only kh==0).
// EPI 0: +bias[m], write conv2-input image. EPI 1: BN-folded scores -> S fp32.
// EPI 2: fp32 out * p0[0].
template <int KTOT, int EPI, int AF32, int KSPLIT>
__global__ __launch_bounds__(256, 2) void gemm_nt(
    const void* __restrict__ Asrc, long long aZS, int aKC,
    const unsigned char* __restrict__ Bimg, long long bZS, int bKC,
    void* __restrict__ out0,
    const float* __restrict__ p0, const float* __restrict__ p1,
    const float* __restrict__ p2, const float* __restrict__ p3) {
  __shared__ __attribute__((aligned(16))) unsigned char smem[49152];
  int t = threadIdx.x;
  int z = blockIdx.z;
  int zb = z, kh = 0;
  if (KSPLIT) { zb = z & 7; kh = z >> 3; }
  int m0 = blockIdx.y * 128, n0 = blockIdx.x * 64;
  int w = t >> 6, lane = t & 63;
  int lm = lane & 15, q = lane >> 4;
  int mh = (w & 1) * 64, nh = (w >> 1) * 32;
  const unsigned char* Abase = (const unsigned char*)Asrc + (size_t)zb * aZS +
      (size_t)(m0 >> 7) * ((size_t)aKC << 15) + (size_t)w * 8192 + (size_t)lane * 16;
  const unsigned char* Bbase = Bimg + (size_t)zb * bZS +
      (size_t)(n0 >> 7) * ((size_t)bKC << 15) + (size_t)(n0 & 127) * 256 +
      (size_t)w * 4096 + (size_t)lane * 16;
  facc acc[4][2] = {};  // [mt][nt]
  for (int k0 = 0; k0 < KTOT; k0 += 64) {
    int kc = (KSPLIT ? kh * (KTOT / 64) : 0) + (k0 >> 6);
    __syncthreads();
    if (AF32) {
      const float* Af = (const float*)Asrc;
#pragma unroll
      for (int j = 0; j < 8; j++) {
        int idx = t + 256 * j;
        int row = idx >> 4, c4 = idx & 15;
        float4 v = *(const float4*)(Af + (size_t)(m0 + row) * KTOT + k0 + c4 * 4);
        unsigned short h0 = bf16_rn(v.x), h1 = bf16_rn(v.y), h2 = bf16_rn(v.z), h3 = bf16_rn(v.w);
        unsigned short l0 = bf16_rn(v.x - __uint_as_float((unsigned)h0 << 16));
        unsigned short l1 = bf16_rn(v.y - __uint_as_float((unsigned)h1 << 16));
        unsigned short l2 = bf16_rn(v.z - __uint_as_float((unsigned)h2 << 16));
        unsigned short l3 = bf16_rn(v.w - __uint_as_float((unsigned)h3 << 16));
        int base = row * 256 + (((c4 >> 1) ^ (row & 7)) * 16) + (c4 & 1) * 8;
        *(ushort4*)(smem + base) = make_ushort4(h0, h1, h2, h3);
        *(ushort4*)(smem + base + 128) = make_ushort4(l0, l1, l2, l3);
      }
    } else {
      const unsigned char* ap = Abase + ((size_t)kc << 15);
#pragma unroll
      for (int j = 0; j < 8; j++) dma16(ap + j * 1024, smem + w * 8192 + j * 1024);
    }
    {
      const unsigned char* bp = Bbase + ((size_t)kc << 15);
#pragma unroll
      for (int j = 0; j < 4; j++) dma16(bp + j * 1024, smem + 32768 + w * 4096 + j * 1024);
    }
    __syncthreads();
#pragma unroll
    for (int ks = 0; ks < 2; ks++) {
      bfrag ah[4], al[4], bh[2], bl[2];
#pragma unroll
      for (int mt = 0; mt < 4; mt++) {
        int m = mh + mt * 16 + lm;
        int phys = ((ks * 4 + q) ^ (m & 7)) * 16;
        const unsigned char* p = smem + m * 256 + phys;
        ah[mt] = *(const bfrag*)p;
        al[mt] = *(const bfrag*)(p + 128);
      }
#pragma unroll
      for (int nt = 0; nt < 2; nt++) {
        int n = nh + nt * 16 + lm;
        int phys = ((ks * 4 + q) ^ (n & 7)) * 16;
        const unsigned char* p = smem + 32768 + n * 256 + phys;
        bh[nt] = *(const bfrag*)p;
        bl[nt] = *(const bfrag*)(p + 128);
      }
#pragma unroll
      for (int mt = 0; mt < 4; mt++)
#pragma unroll
        for (int nt = 0; nt < 2; nt++) {
          acc[mt][nt] = __builtin_amdgcn_mfma_f32_16x16x32_bf16(ah[mt], bh[nt], acc[mt][nt], 0, 0, 0);
          acc[mt][nt] = __builtin_amdgcn_mfma_f32_16x16x32_bf16(ah[mt], bl[nt], acc[mt][nt], 0, 0, 0);
          acc[mt][nt] = __builtin_amdgcn_mfma_f32_16x16x32_bf16(al[mt], bh[nt], acc[mt][nt], 0, 0, 0);
        }
    }
  }
  if (EPI == 0) {
    // write conv2-input image: [g][cich 8][gy 32][gx 32] 128-B entries,
    // slot = chunk ^ ((gx+1)&7) (entry coord sx = gx+1 in consumer LDS).
    unsigned char* Yimg = (unsigned char*)out0;
    int g = zb;
#pragma unroll
    for (int mt = 0; mt < 4; mt++) {
      int mb = m0 + mh + mt * 16 + q * 4;
      int ch = mb >> 5, chunk = (mb >> 3) & 3, e2 = (mb & 7) * 2;
#pragma unroll
      for (int nt = 0; nt < 2; nt++) {
        int px = n0 + nh + nt * 16 + lm;
        int gy = px >> 5, gx = px & 31;
        int slot = chunk ^ ((gx + 1) & 7);
        size_t base = ((size_t)((g * 8 + ch) * 32 + gy)) * 4096 + gx * 128 + slot * 16 + e2;
        unsigned short hh[4], ll[4];
#pragma unroll
        for (int r = 0; r < 4; r++) {
          float v = acc[mt][nt][r] + p0[mb + r];
          hh[r] = bf16_rn(v);
          ll[r] = bf16_rn(v - __uint_as_float((unsigned)hh[r] << 16));
        }
        *(ushort4*)(Yimg + base) = make_ushort4(hh[0], hh[1], hh[2], hh[3]);
        *(ushort4*)(Yimg + (base ^ 64)) = make_ushort4(ll[0], ll[1], ll[2], ll[3]);
      }
    }
  } else if (EPI == 1) {
    float* S = (float*)out0 + (size_t)kh * 2097152;
    const float* stats = p0;
    const float* rowsum = p1;
    const float* gamma = p2;
    const float* bnb = p3;
    float a2v[2], t2v[2], r2v[2];
#pragma unroll
    for (int nt = 0; nt < 2; nt++) {
      int d = n0 + nh + nt * 16 + lm;
      float mu = stats[512 + d] * (1.f / 8192.f);
      float var = stats[1536 + d] * (1.f / 8192.f) - mu * mu;
      float a = gamma[d] * rsqrtf(var + 1e-5f);
      a2v[nt] = a;
      t2v[nt] = bnb[d] - mu * a;
      r2v[nt] = rowsum[(8 + zb) * 512 + d];
    }
#pragma unroll
    for (int mt = 0; mt < 4; mt++)
#pragma unroll
      for (int r = 0; r < 4; r++) {
        int cc = m0 + mh + mt * 16 + q * 4 + r;
        float mu = stats[cc] * (1.f / 8192.f);
        float var = stats[1024 + cc] * (1.f / 8192.f) - mu * mu;
        float a1 = gamma[cc] * rsqrtf(var + 1e-5f);
        float t1 = bnb[cc] - mu * a1;
        float r1 = rowsum[zb * 512 + cc];
#pragma unroll
        for (int nt = 0; nt < 2; nt++) {
          int d = n0 + nh + nt * 16 + lm;
          float sc = a1 * a2v[nt] * acc[mt][nt][r];
          if (kh == 0)
            sc += a1 * t2v[nt] * r1 + t1 * a2v[nt] * r2v[nt] + 1024.f * t1 * t2v[nt];
          S[((size_t)(zb * 512 + cc)) * 512 + d] = sc;
        }
      }
  } else {
    float* O = (float*)out0;
    float sc = p0[0];
#pragma unroll
    for (int mt = 0; mt < 4; mt++)
#pragma unroll
      for (int r = 0; r < 4; r++) {
        int cc = m0 + mh + mt * 16 + q * 4 + r;
#pragma unroll
        for (int nt = 0; nt < 2; nt++) {
          int n = n0 + nh + nt * 16 + lm;
          O[((size_t)(zb * 512 + cc)) * 1024 + n] = sc * acc[mt][nt][r];
        }
      }
  }
}

// conv2 3x3 SAME 256->512 split-bf16 MFMA, round-8 structure:
// A-operand (weights) loaded straight global->VGPR from the register-fragment
// w2s layout with an EXPLICIT one-phase register prefetch (Wc/Wn ping-pong):
// phase p issues the 8 loads for phase p+1, then runs p's 48 MFMAs out of Wc
// (already resident -> no vmcnt stall). Input tile double-buffered in LDS
// (2 x 26112 B); next chunk's DMA is issued mid-chunk (r==3) so the single
// per-chunk __syncthreads drain finds it complete.
__global__ __launch_bounds__(256, 2) void conv3x3_mfma(
    const unsigned char* __restrict__ Yimg, const unsigned short* __restrict__ w2s,
    const float* __restrict__ b2, unsigned char* __restrict__ Fimg,
    float* __restrict__ stats, float* __restrict__ rowsum) {
  __shared__ __attribute__((aligned(16))) unsigned char smem[2][26112];
  int t = threadIdx.x;
  int g = blockIdx.z;
  int panel = blockIdx.y;
  int co_base = panel * 128;
  int y0 = blockIdx.x * 4;
  int w = t >> 6, lane = t & 63;
  int lm = lane & 15, q = lane >> 4;
  int co_half = (w & 1) * 64, px_half = (w >> 1) * 64;
  int px_l[4], row_l[4], x_l[4];
#pragma unroll
  for (int i = 0; i < 4; i++) {
    px_l[i] = px_half + i * 16 + lm;
    row_l[i] = px_l[i] >> 5;
    x_l[i] = px_l[i] & 31;
  }
  // stage one chunk's interior strips into dst (pads/out-of-range stay zero)
  auto stageIn = [&](int ct, unsigned char* dst) {
#pragma unroll
    for (int jj = 0; jj < 6; jj++) {
      int id = w * 6 + jj;
      int strip = id >> 2, part = id & 3;
      int gy = y0 - 1 + strip;
      if ((unsigned)gy < 32u) {
        const unsigned char* srcp = Yimg +
            ((size_t)((g * 8 + ct) * 32 + gy)) * 4096 + part * 1024 + lane * 16;
        dma16(srcp, dst + strip * 4352 + 128 + part * 1024);
      }
    }
  };
  // zero both input buffers once (pads + invalid halo strips stay zero)
  for (int u = t; u < 3264; u += 256)
    *(uint4*)(&smem[0][0] + (size_t)u * 16) = make_uint4(0u, 0u, 0u, 0u);
  __syncthreads();
  stageIn(0, &smem[0][0]);
  __syncthreads();  // vmcnt(0) drain: chunk-0 input resident
  // per-wave weight fragment base: phase P=(panel*8+c)*9+r, coh=w&1
  const unsigned char* wg0 = (const unsigned char*)w2s +
      (size_t)panel * 72 * 16384 + (size_t)(w & 1) * 8192 + (size_t)lane * 16;
  auto loadW = [&](bfrag* W, int phase) {
    const unsigned char* p = wg0 + ((size_t)phase << 14);
#pragma unroll
    for (int u = 0; u < 8; u++) W[u] = *(const bfrag*)(p + u * 1024);
  };
  facc acc[4][4] = {};  // [cotile][pxtile]
  bfrag Wc[8], Wn[8];   // (j,hl): ah[j]=Wc[2j], al[j]=Wc[2j+1]
  loadW(Wc, 0);
#pragma unroll 1
  for (int c = 0; c < 8; c++) {
    const unsigned char* bufp = &smem[c & 1][0];
#pragma unroll
    for (int r = 0; r < 9; r++) {
      const int dy = r / 3, dx = r % 3;
      // prefetch next phase's weight fragments (one-past-the-end read at the
      // very last phase lands in the stats region: in-bounds of ws, discarded)
      loadW(Wn, c * 9 + r + 1);
      if (r == 3 && c < 7) stageIn(c + 1, &smem[(c + 1) & 1][0]);
      bfrag bh[4], bl[4];
#pragma unroll
      for (int i = 0; i < 4; i++) {
        int xh = x_l[i] + dx;
        int entry = (row_l[i] + dy) * 34 + xh;
        const unsigned char* pb = bufp + entry * 128;
        int ph = (q ^ (xh & 7)) * 16;
        bh[i] = *(const bfrag*)(pb + ph);
        bl[i] = *(const bfrag*)(pb + (ph ^ 64));
      }
#pragma unroll
      for (int j = 0; j < 4; j++)
#pragma unroll
        for (int i = 0; i < 4; i++) {
          acc[j][i] = __builtin_amdgcn_mfma_f32_16x16x32_bf16(Wc[2 * j], bh[i], acc[j][i], 0, 0, 0);
          acc[j][i] = __builtin_amdgcn_mfma_f32_16x16x32_bf16(Wc[2 * j], bl[i], acc[j][i], 0, 0, 0);
          acc[j][i] = __builtin_amdgcn_mfma_f32_16x16x32_bf16(Wc[2 * j + 1], bh[i], acc[j][i], 0, 0, 0);
        }
      // rotate prefetch buffer into place (SSA-renamed inside the unrolled
      // r-loop; materializes only at the chunk back-edge)
#pragma unroll
      for (int u = 0; u < 8; u++) Wc[u] = Wn[u];
    }
    __syncthreads();  // drains stage(c+1) DMAs; orders buffer swap
  }
  // epilogue: +bias, LeakyReLU, write F image (scores operand) + stats/rowsums
  int grp = g >> 3;
  int px0 = blockIdx.x * 128;
#pragma unroll
  for (int j = 0; j < 4; j++) {
#pragma unroll
    for (int r = 0; r < 4; r++) {
      int co = co_base + co_half + j * 16 + q * 4 + r;
      int row = co & 127;
      float bb = b2[co];
      float s = 0.f, s2 = 0.f;
#pragma unroll
      for (int i = 0; i < 4; i++) {
        float v = acc[j][i][r] + bb;
        v = v > 0.f ? v : 0.01f * v;
        unsigned short h = bf16_rn(v);
        unsigned short l = bf16_rn(v - __uint_as_float((unsigned)h << 16));
        int px = px0 + px_l[i];
        int kc = px >> 6, ck = (px >> 3) & 7;
        int slot = ck ^ (row & 7);
        size_t byte = (((size_t)(g * 4 + panel) * 16 + kc) * 128 + row) * 256 +
                      slot * 16 + (px & 7) * 2;
        *(unsigned short*)(Fimg + byte) = h;
        *(unsigned short*)(Fimg + byte + 128) = l;
        s += v;
        s2 = fmaf(v, v, s2);
      }
#pragma unroll
      for (int d = 1; d <= 8; d <<= 1) {
        s += __shfl_xor(s, d);
        s2 += __shfl_xor(s2, d);
      }
      if (lm == 0) {
        atomicAdd(&stats[grp * 512 + co], s);
        atomicAdd(&stats[1024 + grp * 512 + co], s2);
        atomicAdd(&rowsum[g * 512 + co], s);
      }
    }
  }
}

// Row softmax over 512 (S0+S1 partials); writes att as pre-swizzled image.
__global__ __launch_bounds__(256) void softmax_rows(const float* __restrict__ S,
                                                    unsigned char* __restrict__ attimg) {
  int rowg = blockIdx.x;  // 0..4095
  int z = rowg >> 9, c = rowg & 511;
  const float* p = S + (size_t)rowg * 512;
  const float* p1 = p + 2097152;
  int t = threadIdx.x;
  float2 va = *(const float2*)(p + 2 * t);
  float2 vb = *(const float2*)(p1 + 2 * t);
  float vx = va.x + vb.x, vy = va.y + vb.y;
  float mx = fmaxf(vx, vy);
#pragma unroll
  for (int d = 32; d >= 1; d >>= 1) mx = fmaxf(mx, __shfl_xor(mx, d));
  __shared__ float sred[8];
  int wave = t >> 6, lane = t & 63;
  if (lane == 0) sred[wave] = mx;
  __syncthreads();
  float m4 = fmaxf(fmaxf(sred[0], sred[1]), fmaxf(sred[2], sred[3]));
  float ex = expf(vx - m4), ey = expf(vy - m4);
  float s = ex + ey;
#pragma unroll
  for (int d = 32; d >= 1; d >>= 1) s += __shfl_xor(s, d);
  if (lane == 0) sred[4 + wave] = s;
  __syncthreads();
  float inv = 1.f / (sred[4] + sred[5] + sred[6] + sred[7]);
  float px_ = ex * inv, py_ = ey * inv;
  unsigned short h0 = bf16_rn(px_), h1 = bf16_rn(py_);
  unsigned short l0 = bf16_rn(px_ - __uint_as_float((unsigned)h0 << 16));
  unsigned short l1 = bf16_rn(py_ - __uint_as_float((unsigned)h1 << 16));
  int rowl = c & 127, panel = c >> 7;
  int d0 = 2 * t;
  int kc = d0 >> 6, ck = (d0 >> 3) & 7;
  int slot = ck ^ (rowl & 7);
  size_t byte = (((size_t)(z * 4 + panel) * 8 + kc) * 128 + rowl) * 256 +
                slot * 16 + (d0 & 7) * 2;
  *(ushort2*)(attimg + byte) = make_ushort2(h0, h1);
  *(ushort2*)(attimg + byte + 128) = make_ushort2(l0, l1);
}

extern "C" void kernel_launch(void* const* d_in, const int* in_sizes, int n_in,
                              void* d_out, int out_size, void* d_ws, size_t ws_size,
                              hipStream_t stream) {
  const float* x = (const float*)d_in[0];
  const float* x1 = (const float*)d_in[1];
  const float* x2 = (const float*)d_in[2];
  const float* w1 = (const float*)d_in[3];
  const float* b1 = (const float*)d_in[4];
  const float* w2 = (const float*)d_in[5];
  const float* b2 = (const float*)d_in[6];
  const float* gamma = (const float*)d_in[7];
  const float* bnb = (const float*)d_in[8];
  const float* beta = (const float*)d_in[9];
  float* out = (float*)d_out;
  unsigned char* wsb = (unsigned char*)d_ws;

  unsigned char* x12timg = wsb;                    // 33,554,432 B (-> F image)
  unsigned char* Fimg = wsb;
  unsigned char* xtimg = wsb;                      // 16,777,216 B (after scores)
  unsigned char* attimg = wsb + 16777216;          // 8,388,608 B (after scores)
  unsigned char* Yimg = wsb + 33554432;            // 16,777,216 B (-> S0/S1)
  float* S = (float*)(wsb + 33554432);             // S0; S1 at +2,097,152 fl
  unsigned short* w2s = (unsigned short*)(wsb + 50331648);
  float* stats = (float*)(wsb + 55050240);         // 2048 fl
  float* rowsum = (float*)(wsb + 55058432);        // 8192 fl

  // prologue: x12t image + w2s fragments + stats zero
  prologue<<<8704, 256, 0, stream>>>(x1, x2, w2, x12timg, w2s, stats);
  // conv1: +b1, emit conv2-input image
  gemm_nt<512, 0, 1, 0><<<dim3(16, 2, 16), 256, 0, stream>>>(
      w1, 0LL, 0, x12timg, 2097152LL, 8, Yimg, b1, nullptr, nullptr, nullptr);
  // conv2 + bias + LeakyReLU -> F image + stats + rowsums
  conv3x3_mfma<<<dim3(8, 4, 16), 256, 0, stream>>>(
      Yimg, w2s, b2, Fimg, stats, rowsum);
  // scores (K-split x2) with BN folded -> S0, S1
  gemm_nt<512, 1, 0, 1><<<dim3(8, 4, 16), 256, 0, stream>>>(
      Fimg, 2097152LL, 16, Fimg + (size_t)8 * 2097152, 2097152LL, 16,
      S, stats, rowsum, gamma, bnb);
  // x -> xt image (F dead; overwrites RF front)
  transpose_split_x<<<dim3(32, 16, 8), 256, 0, stream>>>(x, xtimg);
  // softmax (S0+S1) -> att image
  softmax_rows<<<4096, 256, 0, stream>>>(S, attimg);
  // out: O[c][px] = beta * sum_d att*xt
  gemm_nt<512, 2, 0, 0><<<dim3(16, 4, 8), 256, 0, stream>>>(
      attimg, 1048576LL, 8, xtimg, 2097152LL, 8, out, beta, nullptr, nullptr, nullptr);
}

// Round 3
// 291.327 us; speedup vs baseline: 1.0776x; 1.0776x over previous
//
#include <hip/hip_runtime.h>

// Dims: x,x1,x2:(8,512,32,32) fp32; w1:(256,512,1,1); b1:(256); w2:(512,256,3,3);
// b2:(512); gamma,bn_bias:(512); beta:(1). Out:(8,512,32,32) fp32.
// G = 16 images (8 from x1, 8 from x2), N = 1024 spatial.
//
// GEMM operands (except conv2 weights) are stored as pre-swizzled "LDS images":
// per (z, panel(128 rows), kc(64 k)) a 32 KB block of 128 rows x 256 B; row r
// holds 16 chunks of 16 B at slot ((c&7)^(r&7))|(c&8); hi chunks c=0..7
// (k=c*8+e), lo c=8..15 (always hi+128 B). Staging is then pure global_load_lds.
//
// conv2 weights (w2s, round 9): per (panel, chunk, tap=dy*3+dx) phase
// P = (panel*8+chunk)*9+tap, a 16 KB block of 128 co-entries x 128 B; entry co
// holds 8 slots of 16 B: hi element (q,e) [ci = chunk*32+q*8+e] at slot
// q^(co&7), lo at slot^4, byte e*2 within slot. The block is a LINEAR memcpy
// source for global_load_lds; A-fragment ds_reads use ph=(q^(lm&7))*16, ^64.
//
// ws layout (byte offsets), total 55,091,200 B (unchanged):
//  [0        , 33554432) RF : x12t image -> F image (conv2 out) -> xt image
//                         [0,16777216) + att image [16777216, 25165824)
//  [33554432 , 50331648) RY : Y1 conv-input image (16,777,216 B exactly)
//                         -> S0 fp32 [33554432,+8388608) + S1 [+8388608)
//  [50331648 , 55050240) w2s weight phase blocks (288 x 16384 B)
//  [55050240 , 55058432) stats ; [55058432, 55091200) rowsum

typedef __attribute__((ext_vector_type(8))) short bfrag;   // 8 bf16 = 4 VGPR
typedef __attribute__((ext_vector_type(4))) float facc;    // 4 fp32 acc

__device__ __forceinline__ unsigned short bf16_rn(float v) {
  unsigned u = __float_as_uint(v);
  return (unsigned short)((u + 0x7fffu + ((u >> 16) & 1u)) >> 16);
}

// async global -> LDS, 16 B per lane; global addr is per-lane (include lane*16),
// LDS base is wave-uniform (HW adds lane*16).
__device__ __forceinline__ void dma16(const void* g, const void* lds) {
  __builtin_amdgcn_global_load_lds(
      (const __attribute__((address_space(1))) unsigned int*)g,
      (__attribute__((address_space(3))) unsigned int*)(unsigned int)(unsigned long long)(const char*)lds,
      16, 0, 0);
}

// Prologue: blocks [0,8192): x1/x2 -> x12t image; blocks [8192,8704): w2s + stats zero.
__global__ __launch_bounds__(256) void prologue(
    const float* __restrict__ x1, const float* __restrict__ x2,
    const float* __restrict__ w2, unsigned char* __restrict__ x12timg,
    unsigned short* __restrict__ w2s, float* __restrict__ statsz) {
  int bid = blockIdx.x;
  int t = threadIdx.x;
  if (bid < 8192) {
    __shared__ float tile[32][33];
    int p0 = (bid & 31) * 32, ci0 = ((bid >> 5) & 15) * 32, z = bid >> 9;
    const float* src = (z < 8) ? x1 + (size_t)z * 524288 : x2 + (size_t)(z - 8) * 524288;
    {
      int ci_l = t >> 5, p_l = t & 31;
#pragma unroll
      for (int j = 0; j < 4; j++)
        tile[ci_l + 8 * j][p_l] = src[(size_t)(ci0 + ci_l + 8 * j) * 1024 + p0 + p_l];
    }
    __syncthreads();
    {
      int p_l = t >> 3, cg = (t & 7) * 4;
      unsigned short hh[4], ll[4];
#pragma unroll
      for (int j = 0; j < 4; j++) {
        float v = tile[cg + j][p_l];
        hh[j] = bf16_rn(v);
        ll[j] = bf16_rn(v - __uint_as_float((unsigned)hh[j] << 16));
      }
      int px = p0 + p_l, row = px & 127, panel = px >> 7;
      int c = ci0 + cg, kc = c >> 6, ck = (c >> 3) & 7;
      int slot = ck ^ (row & 7);
      size_t byte = (((size_t)(z * 8 + panel) * 8 + kc) * 128 + row) * 256 + slot * 16 + (c & 7) * 2;
      *(ushort4*)(x12timg + byte) = make_ushort4(hh[0], hh[1], hh[2], hh[3]);
      *(ushort4*)(x12timg + byte + 128) = make_ushort4(ll[0], ll[1], ll[2], ll[3]);
    }
  } else {
    int co = bid - 8192;  // 0..511
    if (co < 40) statsz[co * 256 + t] = 0.f;
    // w2s phase-block layout (round 9): P=(panel*8+chunk)*9+tap;
    // us = P*8192 + co_l*64 + slot*8 + e; slot = q^(co_l&7) hi, ^4 lo.
    int panel = co >> 7, co_l = co & 127;
    int chunk = t >> 5, q = (t >> 3) & 3, e = t & 7;
    int slot = q ^ (co_l & 7);
    const float* src = w2 + ((size_t)co * 256 + t) * 9;
#pragma unroll
    for (int tap = 0; tap < 9; tap++) {
      float v = src[tap];
      unsigned short h = bf16_rn(v);
      unsigned short l = bf16_rn(v - __uint_as_float((unsigned)h << 16));
      int P = (panel * 8 + chunk) * 9 + tap;
      size_t us = (size_t)P * 8192 + co_l * 64 + slot * 8 + e;
      w2s[us] = h;
      w2s[us ^ 32] = l;  // slot^4
    }
  }
}

// x fp32 [z][512 c][1024 px] -> xt image (B operand rows=px, k=c).
__global__ __launch_bounds__(256) void transpose_split_x(
    const float* __restrict__ x, unsigned char* __restrict__ img) {
  __shared__ float tile[32][33];
  int z = blockIdx.z;
  const float* src = x + (size_t)z * 524288;
  int ci0 = blockIdx.y * 32, p0 = blockIdx.x * 32;
  int t = threadIdx.x;
  {
    int ci_l = t >> 5, p_l = t & 31;
#pragma unroll
    for (int j = 0; j < 4; j++)
      tile[ci_l + 8 * j][p_l] = src[(size_t)(ci0 + ci_l + 8 * j) * 1024 + p0 + p_l];
  }
  __syncthreads();
  {
    int p_l = t >> 3, cg = (t & 7) * 4;
    unsigned short hh[4], ll[4];
#pragma unroll
    for (int j = 0; j < 4; j++) {
      float v = tile[cg + j][p_l];
      hh[j] = bf16_rn(v);
      ll[j] = bf16_rn(v - __uint_as_float((unsigned)hh[j] << 16));
    }
    int px = p0 + p_l, row = px & 127, panel = px >> 7;
    int c = ci0 + cg, kc = c >> 6, ck = (c >> 3) & 7;
    int slot = ck ^ (row & 7);
    size_t byte = (((size_t)(z * 8 + panel) * 8 + kc) * 128 + row) * 256 + slot * 16 + (c & 7) * 2;
    *(ushort4*)(img + byte) = make_ushort4(hh[0], hh[1], hh[2], hh[3]);
    *(ushort4*)(img + byte + 128) = make_ushort4(ll[0], ll[1], ll[2], ll[3]);
  }
}

// Split-bf16 3-pass NT MFMA GEMM on pre-swizzled images.
// Block tile 128m x 64n, 256 threads, 4 waves 2x2, wave tile 64m x 32n
// (4x2 tiles of 16x16x32). K-step 64. A/B staged via global_load_lds (image
// memcpy); AF32=1: A is fp32 w1, split in-register. KSPLIT: z = kh*8+zb,
// kc = kh*(KTOT/64)+k0/64, EPI1 partial to S+kh*2097152 (affine only kh==0).
// EPI 0: +bias[m], write conv2-input image. EPI 1: BN-folded scores -> S fp32.
// EPI 2: fp32 out * p0[0].
template <int KTOT, int EPI, int AF32, int KSPLIT>
__global__ __launch_bounds__(256, 2) void gemm_nt(
    const void* __restrict__ Asrc, long long aZS, int aKC,
    const unsigned char* __restrict__ Bimg, long long bZS, int bKC,
    void* __restrict__ out0,
    const float* __restrict__ p0, const float* __restrict__ p1,
    const float* __restrict__ p2, const float* __restrict__ p3) {
  __shared__ __attribute__((aligned(16))) unsigned char smem[49152];
  int t = threadIdx.x;
  int z = blockIdx.z;
  int zb = z, kh = 0;
  if (KSPLIT) { zb = z & 7; kh = z >> 3; }
  int m0 = blockIdx.y * 128, n0 = blockIdx.x * 64;
  int w = t >> 6, lane = t & 63;
  int lm = lane & 15, q = lane >> 4;
  int mh = (w & 1) * 64, nh = (w >> 1) * 32;
  const unsigned char* Abase = (const unsigned char*)Asrc + (size_t)zb * aZS +
      (size_t)(m0 >> 7) * ((size_t)aKC << 15) + (size_t)w * 8192 + (size_t)lane * 16;
  const unsigned char* Bbase = Bimg + (size_t)zb * bZS +
      (size_t)(n0 >> 7) * ((size_t)bKC << 15) + (size_t)(n0 & 127) * 256 +
      (size_t)w * 4096 + (size_t)lane * 16;
  facc acc[4][2] = {};  // [mt][nt]
  for (int k0 = 0; k0 < KTOT; k0 += 64) {
    int kc = (KSPLIT ? kh * (KTOT / 64) : 0) + (k0 >> 6);
    __syncthreads();
    if (AF32) {
      const float* Af = (const float*)Asrc;
#pragma unroll
      for (int j = 0; j < 8; j++) {
        int idx = t + 256 * j;
        int row = idx >> 4, c4 = idx & 15;
        float4 v = *(const float4*)(Af + (size_t)(m0 + row) * KTOT + k0 + c4 * 4);
        unsigned short h0 = bf16_rn(v.x), h1 = bf16_rn(v.y), h2 = bf16_rn(v.z), h3 = bf16_rn(v.w);
        unsigned short l0 = bf16_rn(v.x - __uint_as_float((unsigned)h0 << 16));
        unsigned short l1 = bf16_rn(v.y - __uint_as_float((unsigned)h1 << 16));
        unsigned short l2 = bf16_rn(v.z - __uint_as_float((unsigned)h2 << 16));
        unsigned short l3 = bf16_rn(v.w - __uint_as_float((unsigned)h3 << 16));
        int base = row * 256 + (((c4 >> 1) ^ (row & 7)) * 16) + (c4 & 1) * 8;
        *(ushort4*)(smem + base) = make_ushort4(h0, h1, h2, h3);
        *(ushort4*)(smem + base + 128) = make_ushort4(l0, l1, l2, l3);
      }
    } else {
      const unsigned char* ap = Abase + ((size_t)kc << 15);
#pragma unroll
      for (int j = 0; j < 8; j++) dma16(ap + j * 1024, smem + w * 8192 + j * 1024);
    }
    {
      const unsigned char* bp = Bbase + ((size_t)kc << 15);
#pragma unroll
      for (int j = 0; j < 4; j++) dma16(bp + j * 1024, smem + 32768 + w * 4096 + j * 1024);
    }
    __syncthreads();
#pragma unroll
    for (int ks = 0; ks < 2; ks++) {
      bfrag ah[4], al[4], bh[2], bl[2];
#pragma unroll
      for (int mt = 0; mt < 4; mt++) {
        int m = mh + mt * 16 + lm;
        int phys = ((ks * 4 + q) ^ (m & 7)) * 16;
        const unsigned char* p = smem + m * 256 + phys;
        ah[mt] = *(const bfrag*)p;
        al[mt] = *(const bfrag*)(p + 128);
      }
#pragma unroll
      for (int nt = 0; nt < 2; nt++) {
        int n = nh + nt * 16 + lm;
        int phys = ((ks * 4 + q) ^ (n & 7)) * 16;
        const unsigned char* p = smem + 32768 + n * 256 + phys;
        bh[nt] = *(const bfrag*)p;
        bl[nt] = *(const bfrag*)(p + 128);
      }
#pragma unroll
      for (int mt = 0; mt < 4; mt++)
#pragma unroll
        for (int nt = 0; nt < 2; nt++) {
          acc[mt][nt] = __builtin_amdgcn_mfma_f32_16x16x32_bf16(ah[mt], bh[nt], acc[mt][nt], 0, 0, 0);
          acc[mt][nt] = __builtin_amdgcn_mfma_f32_16x16x32_bf16(ah[mt], bl[nt], acc[mt][nt], 0, 0, 0);
          acc[mt][nt] = __builtin_amdgcn_mfma_f32_16x16x32_bf16(al[mt], bh[nt], acc[mt][nt], 0, 0, 0);
        }
    }
  }
  if (EPI == 0) {
    // write conv2-input image: [g][cich 8][gy 32][gx 32] 128-B entries,
    // slot = chunk ^ ((gx+1)&7) (entry coord sx = gx+1 in consumer LDS).
    unsigned char* Yimg = (unsigned char*)out0;
    int g = zb;
#pragma unroll
    for (int mt = 0; mt < 4; mt++) {
      int mb = m0 + mh + mt * 16 + q * 4;
      int ch = mb >> 5, chunk = (mb >> 3) & 3, e2 = (mb & 7) * 2;
#pragma unroll
      for (int nt = 0; nt < 2; nt++) {
        int px = n0 + nh + nt * 16 + lm;
        int gy = px >> 5, gx = px & 31;
        int slot = chunk ^ ((gx + 1) & 7);
        size_t base = ((size_t)((g * 8 + ch) * 32 + gy)) * 4096 + gx * 128 + slot * 16 + e2;
        unsigned short hh[4], ll[4];
#pragma unroll
        for (int r = 0; r < 4; r++) {
          float v = acc[mt][nt][r] + p0[mb + r];
          hh[r] = bf16_rn(v);
          ll[r] = bf16_rn(v - __uint_as_float((unsigned)hh[r] << 16));
        }
        *(ushort4*)(Yimg + base) = make_ushort4(hh[0], hh[1], hh[2], hh[3]);
        *(ushort4*)(Yimg + (base ^ 64)) = make_ushort4(ll[0], ll[1], ll[2], ll[3]);
      }
    }
  } else if (EPI == 1) {
    float* S = (float*)out0 + (size_t)kh * 2097152;
    const float* stats = p0;
    const float* rowsum = p1;
    const float* gamma = p2;
    const float* bnb = p3;
    float a2v[2], t2v[2], r2v[2];
#pragma unroll
    for (int nt = 0; nt < 2; nt++) {
      int d = n0 + nh + nt * 16 + lm;
      float mu = stats[512 + d] * (1.f / 8192.f);
      float var = stats[1536 + d] * (1.f / 8192.f) - mu * mu;
      float a = gamma[d] * rsqrtf(var + 1e-5f);
      a2v[nt] = a;
      t2v[nt] = bnb[d] - mu * a;
      r2v[nt] = rowsum[(8 + zb) * 512 + d];
    }
#pragma unroll
    for (int mt = 0; mt < 4; mt++)
#pragma unroll
      for (int r = 0; r < 4; r++) {
        int cc = m0 + mh + mt * 16 + q * 4 + r;
        float mu = stats[cc] * (1.f / 8192.f);
        float var = stats[1024 + cc] * (1.f / 8192.f) - mu * mu;
        float a1 = gamma[cc] * rsqrtf(var + 1e-5f);
        float t1 = bnb[cc] - mu * a1;
        float r1 = rowsum[zb * 512 + cc];
#pragma unroll
        for (int nt = 0; nt < 2; nt++) {
          int d = n0 + nh + nt * 16 + lm;
          float sc = a1 * a2v[nt] * acc[mt][nt][r];
          if (kh == 0)
            sc += a1 * t2v[nt] * r1 + t1 * a2v[nt] * r2v[nt] + 1024.f * t1 * t2v[nt];
          S[((size_t)(zb * 512 + cc)) * 512 + d] = sc;
        }
      }
  } else {
    float* O = (float*)out0;
    float sc = p0[0];
#pragma unroll
    for (int mt = 0; mt < 4; mt++)
#pragma unroll
      for (int r = 0; r < 4; r++) {
        int cc = m0 + mh + mt * 16 + q * 4 + r;
#pragma unroll
        for (int nt = 0; nt < 2; nt++) {
          int n = n0 + nh + nt * 16 + lm;
          O[((size_t)(zb * 512 + cc)) * 1024 + n] = sc * acc[mt][nt][r];
        }
      }
  }
}

// conv2 3x3 SAME 256->512 split-bf16 MFMA, round-9 structure:
// everything staged via global_load_lds, but NOTHING is drained hot:
//  - weights: per-dx 16 KB granules, double-buffered; phase p issues p+1.
//  - input: 8-slot strip ring (strips advance 6/chunk); each strip staged
//    >=1 phase (mostly >=3) before first read, into a slot whose last reader
//    finished at an earlier barrier. Invalid edge strips are zero-written.
// One __syncthreads per dx-phase (72 total); every transfer it drains has had
// a full MFMA phase (~1.9k cyc) to complete.
__global__ __launch_bounds__(256, 2) void conv3x3_mfma(
    const unsigned char* __restrict__ Yimg, const unsigned short* __restrict__ w2s,
    const float* __restrict__ b2, unsigned char* __restrict__ Fimg,
    float* __restrict__ stats, float* __restrict__ rowsum) {
  // [0, 34816): input strip ring, 8 slots x 4352 B (34 entries x 128 B)
  // [34816, 67584): weight dbuf, 2 x 16384 B (128 co-entries x 128 B)
  __shared__ __attribute__((aligned(16))) unsigned char smem[67584];
  const int WOFF = 34816;
  int t = threadIdx.x;
  int g = blockIdx.z;
  int panel = blockIdx.y;
  int co_base = panel * 128;
  int y0 = blockIdx.x * 4;
  int w = t >> 6, lane = t & 63;
  int lm = lane & 15, q = lane >> 4;
  int co_half = (w & 1) * 64, px_half = (w >> 1) * 64;
  int pha = (q ^ (lm & 7)) * 16;   // A-fragment hi slot byte (lane-const)
  int px_l[4], row_l[4], x_l[4];
#pragma unroll
  for (int i = 0; i < 4; i++) {
    px_l[i] = px_half + i * 16 + lm;
    row_l[i] = px_l[i] >> 5;
    x_l[i] = px_l[i] & 31;
  }
  const unsigned char* w2sb = (const unsigned char*)w2s + (((size_t)panel * 72) << 14);
  // stage weight phase P (16 KB, linear memcpy) into buffer (P&1)
  auto stageW = [&](int P) {
    const unsigned char* srcp = w2sb + (((size_t)P) << 14) + (w * 4) * 1024 + lane * 16;
    unsigned char* dstp = smem + WOFF + ((P & 1) << 14) + (w * 4) * 1024;
#pragma unroll
    for (int j = 0; j < 4; j++) dma16(srcp + j * 1024, dstp + j * 1024);
  };
  // stage one input strip (4 KB interior; wave w carries part w); invalid
  // rows are zero-written (ring slots rotate, so "stays zero" doesn't hold)
  auto stageStrip = [&](int slot, int gy, int cc) {
    unsigned char* dst = smem + slot * 4352 + 128 + w * 1024;
    if ((unsigned)gy < 32u) {
      const unsigned char* srcp = Yimg +
          ((size_t)((g * 8 + cc) * 32 + gy)) * 4096 + w * 1024 + lane * 16;
      dma16(srcp, dst);
    } else {
      *(uint4*)(dst + lane * 16) = make_uint4(0u, 0u, 0u, 0u);
    }
  };
  // zero the input ring once (pads at entries 0 and 33 of each slot stay zero)
  for (int u = t; u < 2176; u += 256)
    *(uint4*)(smem + (size_t)u * 16) = make_uint4(0u, 0u, 0u, 0u);
  __syncthreads();
  stageW(0);
  stageStrip(0, y0 - 1, 0);
  stageStrip(1, y0 + 0, 0);
  stageStrip(2, y0 + 1, 0);
  stageStrip(3, y0 + 2, 0);
  __syncthreads();  // drain: phase-0 weights + chunk-0 strips 0..3 resident
  facc acc[4][4] = {};  // [cotile][pxtile]
#pragma unroll 1
  for (int c = 0; c < 8; c++) {
    int base6 = (c * 6) & 7;
#pragma unroll
    for (int tap = 0; tap < 9; tap++) {
      const int dy = tap / 3, dx = tap % 3;
      int p = c * 9 + tap;
      if (p < 71) stageW(p + 1);
      if (tap == 0) {
        stageStrip((base6 + 4) & 7, y0 + 3, c);
        stageStrip((base6 + 5) & 7, y0 + 4, c);
        if (c < 7) {
          stageStrip((base6 + 6) & 7, y0 - 1, c + 1);
          stageStrip((base6 + 7) & 7, y0 + 0, c + 1);
        }
      } else if (tap == 3) {
        if (c < 7) stageStrip(base6, y0 + 1, c + 1);        // (base6+8)&7
      } else if (tap == 6) {
        if (c < 7) stageStrip((base6 + 1) & 7, y0 + 2, c + 1);  // (base6+9)&7
      }
      const unsigned char* wb = smem + WOFF + ((p & 1) << 14);
      bfrag ah[4], al[4], bh[4], bl[4];
#pragma unroll
      for (int j = 0; j < 4; j++) {
        int co_r = co_half + j * 16 + lm;
        const unsigned char* pa = wb + co_r * 128;
        ah[j] = *(const bfrag*)(pa + pha);
        al[j] = *(const bfrag*)(pa + (pha ^ 64));
      }
#pragma unroll
      for (int i = 0; i < 4; i++) {
        int xh = x_l[i] + dx;
        int slot = (base6 + row_l[i] + dy) & 7;
        const unsigned char* pb = smem + slot * 4352 + xh * 128;
        int ph = (q ^ (xh & 7)) * 16;
        bh[i] = *(const bfrag*)(pb + ph);
        bl[i] = *(const bfrag*)(pb + (ph ^ 64));
      }
#pragma unroll
      for (int j = 0; j < 4; j++)
#pragma unroll
        for (int i = 0; i < 4; i++) {
          acc[j][i] = __builtin_amdgcn_mfma_f32_16x16x32_bf16(ah[j], bh[i], acc[j][i], 0, 0, 0);
          acc[j][i] = __builtin_amdgcn_mfma_f32_16x16x32_bf16(ah[j], bl[i], acc[j][i], 0, 0, 0);
          acc[j][i] = __builtin_amdgcn_mfma_f32_16x16x32_bf16(al[j], bh[i], acc[j][i], 0, 0, 0);
        }
      __syncthreads();  // drains this phase's issued transfers (already landed)
    }
  }
  // epilogue: +bias, LeakyReLU, write F image (scores operand) + stats/rowsums
  int grp = g >> 3;
  int px0 = blockIdx.x * 128;
#pragma unroll
  for (int j = 0; j < 4; j++) {
#pragma unroll
    for (int r = 0; r < 4; r++) {
      int co = co_base + co_half + j * 16 + q * 4 + r;
      int row = co & 127;
      float bb = b2[co];
      float s = 0.f, s2 = 0.f;
#pragma unroll
      for (int i = 0; i < 4; i++) {
        float v = acc[j][i][r] + bb;
        v = v > 0.f ? v : 0.01f * v;
        unsigned short h = bf16_rn(v);
        unsigned short l = bf16_rn(v - __uint_as_float((unsigned)h << 16));
        int px = px0 + px_l[i];
        int kc = px >> 6, ck = (px >> 3) & 7;
        int slot = ck ^ (row & 7);
        size_t byte = (((size_t)(g * 4 + panel) * 16 + kc) * 128 + row) * 256 +
                      slot * 16 + (px & 7) * 2;
        *(unsigned short*)(Fimg + byte) = h;
        *(unsigned short*)(Fimg + byte + 128) = l;
        s += v;
        s2 = fmaf(v, v, s2);
      }
#pragma unroll
      for (int d = 1; d <= 8; d <<= 1) {
        s += __shfl_xor(s, d);
        s2 += __shfl_xor(s2, d);
      }
      if (lm == 0) {
        atomicAdd(&stats[grp * 512 + co], s);
        atomicAdd(&stats[1024 + grp * 512 + co], s2);
        atomicAdd(&rowsum[g * 512 + co], s);
      }
    }
  }
}

// Row softmax over 512 (S0+S1 partials); writes att as pre-swizzled image.
__global__ __launch_bounds__(256) void softmax_rows(const float* __restrict__ S,
                                                    unsigned char* __restrict__ attimg) {
  int rowg = blockIdx.x;  // 0..4095
  int z = rowg >> 9, c = rowg & 511;
  const float* p = S + (size_t)rowg * 512;
  const float* p1 = p + 2097152;
  int t = threadIdx.x;
  float2 va = *(const float2*)(p + 2 * t);
  float2 vb = *(const float2*)(p1 + 2 * t);
  float vx = va.x + vb.x, vy = va.y + vb.y;
  float mx = fmaxf(vx, vy);
#pragma unroll
  for (int d = 32; d >= 1; d >>= 1) mx = fmaxf(mx, __shfl_xor(mx, d));
  __shared__ float sred[8];
  int wave = t >> 6, lane = t & 63;
  if (lane == 0) sred[wave] = mx;
  __syncthreads();
  float m4 = fmaxf(fmaxf(sred[0], sred[1]), fmaxf(sred[2], sred[3]));
  float ex = expf(vx - m4), ey = expf(vy - m4);
  float s = ex + ey;
#pragma unroll
  for (int d = 32; d >= 1; d >>= 1) s += __shfl_xor(s, d);
  if (lane == 0) sred[4 + wave] = s;
  __syncthreads();
  float inv = 1.f / (sred[4] + sred[5] + sred[6] + sred[7]);
  float px_ = ex * inv, py_ = ey * inv;
  unsigned short h0 = bf16_rn(px_), h1 = bf16_rn(py_);
  unsigned short l0 = bf16_rn(px_ - __uint_as_float((unsigned)h0 << 16));
  unsigned short l1 = bf16_rn(py_ - __uint_as_float((unsigned)h1 << 16));
  int rowl = c & 127, panel = c >> 7;
  int d0 = 2 * t;
  int kc = d0 >> 6, ck = (d0 >> 3) & 7;
  int slot = ck ^ (rowl & 7);
  size_t byte = (((size_t)(z * 4 + panel) * 8 + kc) * 128 + rowl) * 256 +
                slot * 16 + (d0 & 7) * 2;
  *(ushort2*)(attimg + byte) = make_ushort2(h0, h1);
  *(ushort2*)(attimg + byte + 128) = make_ushort2(l0, l1);
}

extern "C" void kernel_launch(void* const* d_in, const int* in_sizes, int n_in,
                              void* d_out, int out_size, void* d_ws, size_t ws_size,
                              hipStream_t stream) {
  const float* x = (const float*)d_in[0];
  const float* x1 = (const float*)d_in[1];
  const float* x2 = (const float*)d_in[2];
  const float* w1 = (const float*)d_in[3];
  const float* b1 = (const float*)d_in[4];
  const float* w2 = (const float*)d_in[5];
  const float* b2 = (const float*)d_in[6];
  const float* gamma = (const float*)d_in[7];
  const float* bnb = (const float*)d_in[8];
  const float* beta = (const float*)d_in[9];
  float* out = (float*)d_out;
  unsigned char* wsb = (unsigned char*)d_ws;

  unsigned char* x12timg = wsb;                    // 33,554,432 B (-> F image)
  unsigned char* Fimg = wsb;
  unsigned char* xtimg = wsb;                      // 16,777,216 B (after scores)
  unsigned char* attimg = wsb + 16777216;          // 8,388,608 B (after scores)
  unsigned char* Yimg = wsb + 33554432;            // 16,777,216 B (-> S0/S1)
  float* S = (float*)(wsb + 33554432);             // S0; S1 at +2,097,152 fl
  unsigned short* w2s = (unsigned short*)(wsb + 50331648);
  float* stats = (float*)(wsb + 55050240);         // 2048 fl
  float* rowsum = (float*)(wsb + 55058432);        // 8192 fl

  // prologue: x12t image + w2s phase blocks + stats zero
  prologue<<<8704, 256, 0, stream>>>(x1, x2, w2, x12timg, w2s, stats);
  // conv1: +b1, emit conv2-input image
  gemm_nt<512, 0, 1, 0><<<dim3(16, 2, 16), 256, 0, stream>>>(
      w1, 0LL, 0, x12timg, 2097152LL, 8, Yimg, b1, nullptr, nullptr, nullptr);
  // conv2 + bias + LeakyReLU -> F image + stats + rowsums
  conv3x3_mfma<<<dim3(8, 4, 16), 256, 0, stream>>>(
      Yimg, w2s, b2, Fimg, stats, rowsum);
  // scores (K-split x2) with BN folded -> S0, S1
  gemm_nt<512, 1, 0, 1><<<dim3(8, 4, 16), 256, 0, stream>>>(
      Fimg, 2097152LL, 16, Fimg + (size_t)8 * 2097152, 2097152LL, 16,
      S, stats, rowsum, gamma, bnb);
  // x -> xt image (F dead; overwrites RF front)
  transpose_split_x<<<dim3(32, 16, 8), 256, 0, stream>>>(x, xtimg);
  // softmax (S0+S1) -> att image
  softmax_rows<<<4096, 256, 0, stream>>>(S, attimg);
  // out: O[c][px] = beta * sum_d att*xt
  gemm_nt<512, 2, 0, 0><<<dim3(16, 4, 8), 256, 0, stream>>>(
      attimg, 1048576LL, 8, xtimg, 2097152LL, 8, out, beta, nullptr, nullptr, nullptr);
}

// Round 4
// 284.765 us; speedup vs baseline: 1.1025x; 1.0230x over previous
//
#include <hip/hip_runtime.h>

// Dims: x,x1,x2:(8,512,32,32) fp32; w1:(256,512,1,1); b1:(256); w2:(512,256,3,3);
// b2:(512); gamma,bn_bias:(512); beta:(1). Out:(8,512,32,32) fp32.
// G = 16 images (8 from x1, 8 from x2), N = 1024 spatial.
//
// GEMM operands (except conv2 weights) are stored as pre-swizzled "LDS images":
// per (z, panel(128 rows), kc(64 k)) a 32 KB block of 128 rows x 256 B; row r
// holds 16 chunks of 16 B at slot ((c&7)^(r&7))|(c&8); hi chunks c=0..7
// (k=c*8+e), lo c=8..15 (always hi+128 B). Staging is then pure global_load_lds.
//
// conv2 weights (w2s): per (panel, chunk, tap=dy*3+dx) phase
// P = (panel*8+chunk)*9+tap, a 16 KB block of 128 co-entries x 128 B; entry co
// holds 8 slots of 16 B: hi element (q,e) [ci = chunk*32+q*8+e] at slot
// q^(co&7), lo at slot^4, byte e*2 within slot. The block is a LINEAR memcpy
// source for global_load_lds; A-fragment ds_reads use ph=(q^(lm&7))*16, ^64.
//
// conv round 10: fragment reads are REGISTER-PIPELINED one phase ahead with a
// static-parity ping-pong set (no copies -> compiler can't collapse it): the
// 16 ds_reads for phase p+1 issue before the 48 MFMAs of phase p (which have
// no outstanding lgkm deps), so LDS-read time hides under MFMA time.
//
// ws layout (byte offsets), total 55,091,200 B (unchanged):
//  [0        , 33554432) RF : x12t image -> F image (conv2 out) -> xt image
//                         [0,16777216) + att image [16777216, 25165824)
//  [33554432 , 50331648) RY : Y1 conv-input image (16,777,216 B exactly)
//                         -> S0 fp32 [33554432,+8388608) + S1 [+8388608)
//  [50331648 , 55050240) w2s weight phase blocks (288 x 16384 B)
//  [55050240 , 55058432) stats ; [55058432, 55091200) rowsum

typedef __attribute__((ext_vector_type(8))) short bfrag;   // 8 bf16 = 4 VGPR
typedef __attribute__((ext_vector_type(4))) float facc;    // 4 fp32 acc

__device__ __forceinline__ unsigned short bf16_rn(float v) {
  unsigned u = __float_as_uint(v);
  return (unsigned short)((u + 0x7fffu + ((u >> 16) & 1u)) >> 16);
}

// async global -> LDS, 16 B per lane; global addr is per-lane (include lane*16),
// LDS base is wave-uniform (HW adds lane*16).
__device__ __forceinline__ void dma16(const void* g, const void* lds) {
  __builtin_amdgcn_global_load_lds(
      (const __attribute__((address_space(1))) unsigned int*)g,
      (__attribute__((address_space(3))) unsigned int*)(unsigned int)(unsigned long long)(const char*)lds,
      16, 0, 0);
}

// Prologue: blocks [0,8192): x1/x2 -> x12t image; blocks [8192,8704): w2s + stats zero.
__global__ __launch_bounds__(256) void prologue(
    const float* __restrict__ x1, const float* __restrict__ x2,
    const float* __restrict__ w2, unsigned char* __restrict__ x12timg,
    unsigned short* __restrict__ w2s, float* __restrict__ statsz) {
  int bid = blockIdx.x;
  int t = threadIdx.x;
  if (bid < 8192) {
    __shared__ float tile[32][33];
    int p0 = (bid & 31) * 32, ci0 = ((bid >> 5) & 15) * 32, z = bid >> 9;
    const float* src = (z < 8) ? x1 + (size_t)z * 524288 : x2 + (size_t)(z - 8) * 524288;
    {
      int ci_l = t >> 5, p_l = t & 31;
#pragma unroll
      for (int j = 0; j < 4; j++)
        tile[ci_l + 8 * j][p_l] = src[(size_t)(ci0 + ci_l + 8 * j) * 1024 + p0 + p_l];
    }
    __syncthreads();
    {
      int p_l = t >> 3, cg = (t & 7) * 4;
      unsigned short hh[4], ll[4];
#pragma unroll
      for (int j = 0; j < 4; j++) {
        float v = tile[cg + j][p_l];
        hh[j] = bf16_rn(v);
        ll[j] = bf16_rn(v - __uint_as_float((unsigned)hh[j] << 16));
      }
      int px = p0 + p_l, row = px & 127, panel = px >> 7;
      int c = ci0 + cg, kc = c >> 6, ck = (c >> 3) & 7;
      int slot = ck ^ (row & 7);
      size_t byte = (((size_t)(z * 8 + panel) * 8 + kc) * 128 + row) * 256 + slot * 16 + (c & 7) * 2;
      *(ushort4*)(x12timg + byte) = make_ushort4(hh[0], hh[1], hh[2], hh[3]);
      *(ushort4*)(x12timg + byte + 128) = make_ushort4(ll[0], ll[1], ll[2], ll[3]);
    }
  } else {
    int co = bid - 8192;  // 0..511
    if (co < 40) statsz[co * 256 + t] = 0.f;
    // w2s phase-block layout: P=(panel*8+chunk)*9+tap;
    // us = P*8192 + co_l*64 + slot*8 + e; slot = q^(co_l&7) hi, ^4 lo.
    int panel = co >> 7, co_l = co & 127;
    int chunk = t >> 5, q = (t >> 3) & 3, e = t & 7;
    int slot = q ^ (co_l & 7);
    const float* src = w2 + ((size_t)co * 256 + t) * 9;
#pragma unroll
    for (int tap = 0; tap < 9; tap++) {
      float v = src[tap];
      unsigned short h = bf16_rn(v);
      unsigned short l = bf16_rn(v - __uint_as_float((unsigned)h << 16));
      int P = (panel * 8 + chunk) * 9 + tap;
      size_t us = (size_t)P * 8192 + co_l * 64 + slot * 8 + e;
      w2s[us] = h;
      w2s[us ^ 32] = l;  // slot^4
    }
  }
}

// x fp32 [z][512 c][1024 px] -> xt image (B operand rows=px, k=c).
__global__ __launch_bounds__(256) void transpose_split_x(
    const float* __restrict__ x, unsigned char* __restrict__ img) {
  __shared__ float tile[32][33];
  int z = blockIdx.z;
  const float* src = x + (size_t)z * 524288;
  int ci0 = blockIdx.y * 32, p0 = blockIdx.x * 32;
  int t = threadIdx.x;
  {
    int ci_l = t >> 5, p_l = t & 31;
#pragma unroll
    for (int j = 0; j < 4; j++)
      tile[ci_l + 8 * j][p_l] = src[(size_t)(ci0 + ci_l + 8 * j) * 1024 + p0 + p_l];
  }
  __syncthreads();
  {
    int p_l = t >> 3, cg = (t & 7) * 4;
    unsigned short hh[4], ll[4];
#pragma unroll
    for (int j = 0; j < 4; j++) {
      float v = tile[cg + j][p_l];
      hh[j] = bf16_rn(v);
      ll[j] = bf16_rn(v - __uint_as_float((unsigned)hh[j] << 16));
    }
    int px = p0 + p_l, row = px & 127, panel = px >> 7;
    int c = ci0 + cg, kc = c >> 6, ck = (c >> 3) & 7;
    int slot = ck ^ (row & 7);
    size_t byte = (((size_t)(z * 8 + panel) * 8 + kc) * 128 + row) * 256 + slot * 16 + (c & 7) * 2;
    *(ushort4*)(img + byte) = make_ushort4(hh[0], hh[1], hh[2], hh[3]);
    *(ushort4*)(img + byte + 128) = make_ushort4(ll[0], ll[1], ll[2], ll[3]);
  }
}

// Split-bf16 3-pass NT MFMA GEMM on pre-swizzled images.
// Block tile 128m x 64n, 256 threads, 4 waves 2x2, wave tile 64m x 32n
// (4x2 tiles of 16x16x32). K-step 64. A/B staged via global_load_lds (image
// memcpy); AF32=1: A is fp32 w1, split in-register. KSPLIT: z = kh*8+zb,
// kc = kh*(KTOT/64)+k0/64, EPI1 partial to S+kh*2097152 (affine only kh==0).
// EPI 0: +bias[m], write conv2-input image. EPI 1: BN-folded scores -> S fp32.
// EPI 2: fp32 out * p0[0].
template <int KTOT, int EPI, int AF32, int KSPLIT>
__global__ __launch_bounds__(256, 2) void gemm_nt(
    const void* __restrict__ Asrc, long long aZS, int aKC,
    const unsigned char* __restrict__ Bimg, long long bZS, int bKC,
    void* __restrict__ out0,
    const float* __restrict__ p0, const float* __restrict__ p1,
    const float* __restrict__ p2, const float* __restrict__ p3) {
  __shared__ __attribute__((aligned(16))) unsigned char smem[49152];
  int t = threadIdx.x;
  int z = blockIdx.z;
  int zb = z, kh = 0;
  if (KSPLIT) { zb = z & 7; kh = z >> 3; }
  int m0 = blockIdx.y * 128, n0 = blockIdx.x * 64;
  int w = t >> 6, lane = t & 63;
  int lm = lane & 15, q = lane >> 4;
  int mh = (w & 1) * 64, nh = (w >> 1) * 32;
  const unsigned char* Abase = (const unsigned char*)Asrc + (size_t)zb * aZS +
      (size_t)(m0 >> 7) * ((size_t)aKC << 15) + (size_t)w * 8192 + (size_t)lane * 16;
  const unsigned char* Bbase = Bimg + (size_t)zb * bZS +
      (size_t)(n0 >> 7) * ((size_t)bKC << 15) + (size_t)(n0 & 127) * 256 +
      (size_t)w * 4096 + (size_t)lane * 16;
  facc acc[4][2] = {};  // [mt][nt]
  for (int k0 = 0; k0 < KTOT; k0 += 64) {
    int kc = (KSPLIT ? kh * (KTOT / 64) : 0) + (k0 >> 6);
    __syncthreads();
    if (AF32) {
      const float* Af = (const float*)Asrc;
#pragma unroll
      for (int j = 0; j < 8; j++) {
        int idx = t + 256 * j;
        int row = idx >> 4, c4 = idx & 15;
        float4 v = *(const float4*)(Af + (size_t)(m0 + row) * KTOT + k0 + c4 * 4);
        unsigned short h0 = bf16_rn(v.x), h1 = bf16_rn(v.y), h2 = bf16_rn(v.z), h3 = bf16_rn(v.w);
        unsigned short l0 = bf16_rn(v.x - __uint_as_float((unsigned)h0 << 16));
        unsigned short l1 = bf16_rn(v.y - __uint_as_float((unsigned)h1 << 16));
        unsigned short l2 = bf16_rn(v.z - __uint_as_float((unsigned)h2 << 16));
        unsigned short l3 = bf16_rn(v.w - __uint_as_float((unsigned)h3 << 16));
        int base = row * 256 + (((c4 >> 1) ^ (row & 7)) * 16) + (c4 & 1) * 8;
        *(ushort4*)(smem + base) = make_ushort4(h0, h1, h2, h3);
        *(ushort4*)(smem + base + 128) = make_ushort4(l0, l1, l2, l3);
      }
    } else {
      const unsigned char* ap = Abase + ((size_t)kc << 15);
#pragma unroll
      for (int j = 0; j < 8; j++) dma16(ap + j * 1024, smem + w * 8192 + j * 1024);
    }
    {
      const unsigned char* bp = Bbase + ((size_t)kc << 15);
#pragma unroll
      for (int j = 0; j < 4; j++) dma16(bp + j * 1024, smem + 32768 + w * 4096 + j * 1024);
    }
    __syncthreads();
#pragma unroll
    for (int ks = 0; ks < 2; ks++) {
      bfrag ah[4], al[4], bh[2], bl[2];
#pragma unroll
      for (int mt = 0; mt < 4; mt++) {
        int m = mh + mt * 16 + lm;
        int phys = ((ks * 4 + q) ^ (m & 7)) * 16;
        const unsigned char* p = smem + m * 256 + phys;
        ah[mt] = *(const bfrag*)p;
        al[mt] = *(const bfrag*)(p + 128);
      }
#pragma unroll
      for (int nt = 0; nt < 2; nt++) {
        int n = nh + nt * 16 + lm;
        int phys = ((ks * 4 + q) ^ (n & 7)) * 16;
        const unsigned char* p = smem + 32768 + n * 256 + phys;
        bh[nt] = *(const bfrag*)p;
        bl[nt] = *(const bfrag*)(p + 128);
      }
#pragma unroll
      for (int mt = 0; mt < 4; mt++)
#pragma unroll
        for (int nt = 0; nt < 2; nt++) {
          acc[mt][nt] = __builtin_amdgcn_mfma_f32_16x16x32_bf16(ah[mt], bh[nt], acc[mt][nt], 0, 0, 0);
          acc[mt][nt] = __builtin_amdgcn_mfma_f32_16x16x32_bf16(ah[mt], bl[nt], acc[mt][nt], 0, 0, 0);
          acc[mt][nt] = __builtin_amdgcn_mfma_f32_16x16x32_bf16(al[mt], bh[nt], acc[mt][nt], 0, 0, 0);
        }
    }
  }
  if (EPI == 0) {
    // write conv2-input image: [g][cich 8][gy 32][gx 32] 128-B entries,
    // slot = chunk ^ ((gx+1)&7) (entry coord sx = gx+1 in consumer LDS).
    unsigned char* Yimg = (unsigned char*)out0;
    int g = zb;
#pragma unroll
    for (int mt = 0; mt < 4; mt++) {
      int mb = m0 + mh + mt * 16 + q * 4;
      int ch = mb >> 5, chunk = (mb >> 3) & 3, e2 = (mb & 7) * 2;
#pragma unroll
      for (int nt = 0; nt < 2; nt++) {
        int px = n0 + nh + nt * 16 + lm;
        int gy = px >> 5, gx = px & 31;
        int slot = chunk ^ ((gx + 1) & 7);
        size_t base = ((size_t)((g * 8 + ch) * 32 + gy)) * 4096 + gx * 128 + slot * 16 + e2;
        unsigned short hh[4], ll[4];
#pragma unroll
        for (int r = 0; r < 4; r++) {
          float v = acc[mt][nt][r] + p0[mb + r];
          hh[r] = bf16_rn(v);
          ll[r] = bf16_rn(v - __uint_as_float((unsigned)hh[r] << 16));
        }
        *(ushort4*)(Yimg + base) = make_ushort4(hh[0], hh[1], hh[2], hh[3]);
        *(ushort4*)(Yimg + (base ^ 64)) = make_ushort4(ll[0], ll[1], ll[2], ll[3]);
      }
    }
  } else if (EPI == 1) {
    float* S = (float*)out0 + (size_t)kh * 2097152;
    const float* stats = p0;
    const float* rowsum = p1;
    const float* gamma = p2;
    const float* bnb = p3;
    float a2v[2], t2v[2], r2v[2];
#pragma unroll
    for (int nt = 0; nt < 2; nt++) {
      int d = n0 + nh + nt * 16 + lm;
      float mu = stats[512 + d] * (1.f / 8192.f);
      float var = stats[1536 + d] * (1.f / 8192.f) - mu * mu;
      float a = gamma[d] * rsqrtf(var + 1e-5f);
      a2v[nt] = a;
      t2v[nt] = bnb[d] - mu * a;
      r2v[nt] = rowsum[(8 + zb) * 512 + d];
    }
#pragma unroll
    for (int mt = 0; mt < 4; mt++)
#pragma unroll
      for (int r = 0; r < 4; r++) {
        int cc = m0 + mh + mt * 16 + q * 4 + r;
        float mu = stats[cc] * (1.f / 8192.f);
        float var = stats[1024 + cc] * (1.f / 8192.f) - mu * mu;
        float a1 = gamma[cc] * rsqrtf(var + 1e-5f);
        float t1 = bnb[cc] - mu * a1;
        float r1 = rowsum[zb * 512 + cc];
#pragma unroll
        for (int nt = 0; nt < 2; nt++) {
          int d = n0 + nh + nt * 16 + lm;
          float sc = a1 * a2v[nt] * acc[mt][nt][r];
          if (kh == 0)
            sc += a1 * t2v[nt] * r1 + t1 * a2v[nt] * r2v[nt] + 1024.f * t1 * t2v[nt];
          S[((size_t)(zb * 512 + cc)) * 512 + d] = sc;
        }
      }
  } else {
    float* O = (float*)out0;
    float sc = p0[0];
#pragma unroll
    for (int mt = 0; mt < 4; mt++)
#pragma unroll
      for (int r = 0; r < 4; r++) {
        int cc = m0 + mh + mt * 16 + q * 4 + r;
#pragma unroll
        for (int nt = 0; nt < 2; nt++) {
          int n = n0 + nh + nt * 16 + lm;
          O[((size_t)(zb * 512 + cc)) * 1024 + n] = sc * acc[mt][nt][r];
        }
      }
  }
}

// Read the 16 fragments for phase (CN, TAPN) into register set S (static).
#define READ_FRAGS(S, CN, TAPN)                                                 \
  {                                                                             \
    const int dyn_ = (TAPN) / 3, dxn_ = (TAPN) % 3;                             \
    int b6n_ = ((CN) * 6) & 7;                                                  \
    const unsigned char* wbn_ =                                                 \
        smem + WOFF + (((((CN) * 9 + (TAPN)) & 1)) << 14);                      \
    _Pragma("unroll") for (int j_ = 0; j_ < 4; j_++) {                          \
      const unsigned char* pa_ = wbn_ + (co_half + j_ * 16 + lm) * 128;         \
      fAh[S][j_] = *(const bfrag*)(pa_ + pha);                                  \
      fAl[S][j_] = *(const bfrag*)(pa_ + (pha ^ 64));                           \
    }                                                                           \
    _Pragma("unroll") for (int i_ = 0; i_ < 4; i_++) {                          \
      int xh_ = x_l[i_] + dxn_;                                                 \
      int slot_ = (b6n_ + row_l[i_] + dyn_) & 7;                                \
      const unsigned char* pb_ = smem + slot_ * 4352 + xh_ * 128;               \
      int ph_ = (q ^ (xh_ & 7)) * 16;                                           \
      fBh[S][i_] = *(const bfrag*)(pb_ + ph_);                                  \
      fBl[S][i_] = *(const bfrag*)(pb_ + (ph_ ^ 64));                           \
    }                                                                           \
  }

// conv2 3x3 SAME 256->512 split-bf16 MFMA, round-10 structure:
// global_load_lds staging (weights dbuf 2 phases ahead, input 8-slot strip
// ring) + REGISTER-PIPELINED fragment reads: phase p's body issues the 16
// ds_reads for phase p+1 (static-parity ping-pong set, no copies), then runs
// p's 48 MFMAs from registers with no outstanding lgkm deps -> LDS-read time
// hides under MFMA time. One __syncthreads per phase (72 total).
__global__ __launch_bounds__(256, 2) void conv3x3_mfma(
    const unsigned char* __restrict__ Yimg, const unsigned short* __restrict__ w2s,
    const float* __restrict__ b2, unsigned char* __restrict__ Fimg,
    float* __restrict__ stats, float* __restrict__ rowsum) {
  // [0, 34816): input strip ring, 8 slots x 4352 B (34 entries x 128 B)
  // [34816, 67584): weight dbuf, 2 x 16384 B (128 co-entries x 128 B)
  __shared__ __attribute__((aligned(16))) unsigned char smem[67584];
  const int WOFF = 34816;
  int t = threadIdx.x;
  int g = blockIdx.z;
  int panel = blockIdx.y;
  int co_base = panel * 128;
  int y0 = blockIdx.x * 4;
  int w = t >> 6, lane = t & 63;
  int lm = lane & 15, q = lane >> 4;
  int co_half = (w & 1) * 64, px_half = (w >> 1) * 64;
  int pha = (q ^ (lm & 7)) * 16;   // A-fragment hi slot byte (lane-const)
  int px_l[4], row_l[4], x_l[4];
#pragma unroll
  for (int i = 0; i < 4; i++) {
    px_l[i] = px_half + i * 16 + lm;
    row_l[i] = px_l[i] >> 5;
    x_l[i] = px_l[i] & 31;
  }
  const unsigned char* w2sb = (const unsigned char*)w2s + (((size_t)panel * 72) << 14);
  // stage weight phase P (16 KB, linear memcpy) into buffer (P&1)
  auto stageW = [&](int P) {
    const unsigned char* srcp = w2sb + (((size_t)P) << 14) + (w * 4) * 1024 + lane * 16;
    unsigned char* dstp = smem + WOFF + ((P & 1) << 14) + (w * 4) * 1024;
#pragma unroll
    for (int j = 0; j < 4; j++) dma16(srcp + j * 1024, dstp + j * 1024);
  };
  // stage one input strip (4 KB interior; wave w carries part w); invalid
  // rows are zero-written (ring slots rotate, so "stays zero" doesn't hold)
  auto stageStrip = [&](int slot, int gy, int cc) {
    unsigned char* dst = smem + slot * 4352 + 128 + w * 1024;
    if ((unsigned)gy < 32u) {
      const unsigned char* srcp = Yimg +
          ((size_t)((g * 8 + cc) * 32 + gy)) * 4096 + w * 1024 + lane * 16;
      dma16(srcp, dst);
    } else {
      *(uint4*)(dst + lane * 16) = make_uint4(0u, 0u, 0u, 0u);
    }
  };
  // zero the input ring once (pads at entries 0 and 33 of each slot stay zero)
  for (int u = t; u < 2176; u += 256)
    *(uint4*)(smem + (size_t)u * 16) = make_uint4(0u, 0u, 0u, 0u);
  __syncthreads();
  stageW(0);
  stageW(1);
  stageStrip(0, y0 - 1, 0);
  stageStrip(1, y0 + 0, 0);
  stageStrip(2, y0 + 1, 0);
  stageStrip(3, y0 + 2, 0);
  __syncthreads();  // drain: W(0), W(1), chunk-0 strips 0..3 resident
  facc acc[4][4] = {};       // [cotile][pxtile]
  bfrag fAh[2][4], fAl[2][4], fBh[2][4], fBl[2][4];  // parity ping-pong sets
  READ_FRAGS(0, 0, 0)        // fragments for phase 0 -> set 0
#pragma unroll 1
  for (int cc = 0; cc < 4; cc++) {
#pragma unroll
    for (int half = 0; half < 2; half++) {
#pragma unroll
      for (int tap = 0; tap < 9; tap++) {
        const int parity = (half + tap) & 1;  // == (c*9+tap)&1, static
        int c = cc * 2 + half;
        int p = c * 9 + tap;
        // stage weights two phases ahead (into buffer (p&1): its LDS reads
        // finished during phase p-1)
        if (p < 70) stageW(p + 2);
        // stage input strips per liveness schedule
        int base6 = (c * 6) & 7;
        if (tap == 0) {
          stageStrip((base6 + 4) & 7, y0 + 3, c);
          stageStrip((base6 + 5) & 7, y0 + 4, c);
          if (c < 7) {
            stageStrip((base6 + 6) & 7, y0 - 1, c + 1);
            stageStrip((base6 + 7) & 7, y0 + 0, c + 1);
          }
        } else if (tap == 3) {
          if (c < 7) stageStrip(base6, y0 + 1, c + 1);        // (base6+8)&7
        } else if (tap == 6) {
          if (c < 7) stageStrip((base6 + 1) & 7, y0 + 2, c + 1);  // (base6+9)&7
        }
        // issue next phase's fragment reads (overlap with this phase's MFMAs)
        if (p < 71) {
          if (tap < 8) {
            READ_FRAGS(parity ^ 1, c, tap + 1)
          } else {
            READ_FRAGS(parity ^ 1, c + 1, 0)
          }
        }
        // 48 MFMAs on the current set (registers, no lgkm deps)
#pragma unroll
        for (int j = 0; j < 4; j++)
#pragma unroll
          for (int i = 0; i < 4; i++) {
            acc[j][i] = __builtin_amdgcn_mfma_f32_16x16x32_bf16(fAh[parity][j], fBh[parity][i], acc[j][i], 0, 0, 0);
            acc[j][i] = __builtin_amdgcn_mfma_f32_16x16x32_bf16(fAh[parity][j], fBl[parity][i], acc[j][i], 0, 0, 0);
            acc[j][i] = __builtin_amdgcn_mfma_f32_16x16x32_bf16(fAl[parity][j], fBh[parity][i], acc[j][i], 0, 0, 0);
          }
        __syncthreads();  // drains this phase's DMAs + this phase's ds_reads
      }
    }
  }
  // epilogue: +bias, LeakyReLU, write F image (scores operand) + stats/rowsums
  int grp = g >> 3;
  int px0 = blockIdx.x * 128;
#pragma unroll
  for (int j = 0; j < 4; j++) {
#pragma unroll
    for (int r = 0; r < 4; r++) {
      int co = co_base + co_half + j * 16 + q * 4 + r;
      int row = co & 127;
      float bb = b2[co];
      float s = 0.f, s2 = 0.f;
#pragma unroll
      for (int i = 0; i < 4; i++) {
        float v = acc[j][i][r] + bb;
        v = v > 0.f ? v : 0.01f * v;
        unsigned short h = bf16_rn(v);
        unsigned short l = bf16_rn(v - __uint_as_float((unsigned)h << 16));
        int px = px0 + px_l[i];
        int kc = px >> 6, ck = (px >> 3) & 7;
        int slot = ck ^ (row & 7);
        size_t byte = (((size_t)(g * 4 + panel) * 16 + kc) * 128 + row) * 256 +
                      slot * 16 + (px & 7) * 2;
        *(unsigned short*)(Fimg + byte) = h;
        *(unsigned short*)(Fimg + byte + 128) = l;
        s += v;
        s2 = fmaf(v, v, s2);
      }
#pragma unroll
      for (int d = 1; d <= 8; d <<= 1) {
        s += __shfl_xor(s, d);
        s2 += __shfl_xor(s2, d);
      }
      if (lm == 0) {
        atomicAdd(&stats[grp * 512 + co], s);
        atomicAdd(&stats[1024 + grp * 512 + co], s2);
        atomicAdd(&rowsum[g * 512 + co], s);
      }
    }
  }
}

// Row softmax over 512 (S0+S1 partials); writes att as pre-swizzled image.
__global__ __launch_bounds__(256) void softmax_rows(const float* __restrict__ S,
                                                    unsigned char* __restrict__ attimg) {
  int rowg = blockIdx.x;  // 0..4095
  int z = rowg >> 9, c = rowg & 511;
  const float* p = S + (size_t)rowg * 512;
  const float* p1 = p + 2097152;
  int t = threadIdx.x;
  float2 va = *(const float2*)(p + 2 * t);
  float2 vb = *(const float2*)(p1 + 2 * t);
  float vx = va.x + vb.x, vy = va.y + vb.y;
  float mx = fmaxf(vx, vy);
#pragma unroll
  for (int d = 32; d >= 1; d >>= 1) mx = fmaxf(mx, __shfl_xor(mx, d));
  __shared__ float sred[8];
  int wave = t >> 6, lane = t & 63;
  if (lane == 0) sred[wave] = mx;
  __syncthreads();
  float m4 = fmaxf(fmaxf(sred[0], sred[1]), fmaxf(sred[2], sred[3]));
  float ex = expf(vx - m4), ey = expf(vy - m4);
  float s = ex + ey;
#pragma unroll
  for (int d = 32; d >= 1; d >>= 1) s += __shfl_xor(s, d);
  if (lane == 0) sred[4 + wave] = s;
  __syncthreads();
  float inv = 1.f / (sred[4] + sred[5] + sred[6] + sred[7]);
  float px_ = ex * inv, py_ = ey * inv;
  unsigned short h0 = bf16_rn(px_), h1 = bf16_rn(py_);
  unsigned short l0 = bf16_rn(px_ - __uint_as_float((unsigned)h0 << 16));
  unsigned short l1 = bf16_rn(py_ - __uint_as_float((unsigned)h1 << 16));
  int rowl = c & 127, panel = c >> 7;
  int d0 = 2 * t;
  int kc = d0 >> 6, ck = (d0 >> 3) & 7;
  int slot = ck ^ (rowl & 7);
  size_t byte = (((size_t)(z * 4 + panel) * 8 + kc) * 128 + rowl) * 256 +
                slot * 16 + (d0 & 7) * 2;
  *(ushort2*)(attimg + byte) = make_ushort2(h0, h1);
  *(ushort2*)(attimg + byte + 128) = make_ushort2(l0, l1);
}

extern "C" void kernel_launch(void* const* d_in, const int* in_sizes, int n_in,
                              void* d_out, int out_size, void* d_ws, size_t ws_size,
                              hipStream_t stream) {
  const float* x = (const float*)d_in[0];
  const float* x1 = (const float*)d_in[1];
  const float* x2 = (const float*)d_in[2];
  const float* w1 = (const float*)d_in[3];
  const float* b1 = (const float*)d_in[4];
  const float* w2 = (const float*)d_in[5];
  const float* b2 = (const float*)d_in[6];
  const float* gamma = (const float*)d_in[7];
  const float* bnb = (const float*)d_in[8];
  const float* beta = (const float*)d_in[9];
  float* out = (float*)d_out;
  unsigned char* wsb = (unsigned char*)d_ws;

  unsigned char* x12timg = wsb;                    // 33,554,432 B (-> F image)
  unsigned char* Fimg = wsb;
  unsigned char* xtimg = wsb;                      // 16,777,216 B (after scores)
  unsigned char* attimg = wsb + 16777216;          // 8,388,608 B (after scores)
  unsigned char* Yimg = wsb + 33554432;            // 16,777,216 B (-> S0/S1)
  float* S = (float*)(wsb + 33554432);             // S0; S1 at +2,097,152 fl
  unsigned short* w2s = (unsigned short*)(wsb + 50331648);
  float* stats = (float*)(wsb + 55050240);         // 2048 fl
  float* rowsum = (float*)(wsb + 55058432);        // 8192 fl

  // prologue: x12t image + w2s phase blocks + stats zero
  prologue<<<8704, 256, 0, stream>>>(x1, x2, w2, x12timg, w2s, stats);
  // conv1: +b1, emit conv2-input image
  gemm_nt<512, 0, 1, 0><<<dim3(16, 2, 16), 256, 0, stream>>>(
      w1, 0LL, 0, x12timg, 2097152LL, 8, Yimg, b1, nullptr, nullptr, nullptr);
  // conv2 + bias + LeakyReLU -> F image + stats + rowsums
  conv3x3_mfma<<<dim3(8, 4, 16), 256, 0, stream>>>(
      Yimg, w2s, b2, Fimg, stats, rowsum);
  // scores (K-split x2) with BN folded -> S0, S1
  gemm_nt<512, 1, 0, 1><<<dim3(8, 4, 16), 256, 0, stream>>>(
      Fimg, 2097152LL, 16, Fimg + (size_t)8 * 2097152, 2097152LL, 16,
      S, stats, rowsum, gamma, bnb);
  // x -> xt image (F dead; overwrites RF front)
  transpose_split_x<<<dim3(32, 16, 8), 256, 0, stream>>>(x, xtimg);
  // softmax (S0+S1) -> att image
  softmax_rows<<<4096, 256, 0, stream>>>(S, attimg);
  // out: O[c][px] = beta * sum_d att*xt
  gemm_nt<512, 2, 0, 0><<<dim3(16, 4, 8), 256, 0, stream>>>(
      attimg, 1048576LL, 8, xtimg, 2097152LL, 8, out, beta, nullptr, nullptr, nullptr);
}